// Round 10
// baseline (235.335 us; speedup 1.0000x reference)
//
#include <hip/hip_runtime.h>
#include <cstdint>
#include <cstddef>

#define NROWS 262144
#define EMB 256
#define NB 512
#define NCOPY 8
#define TPB_TILES 4
#define SLOPE 0.01f

typedef __attribute__((ext_vector_type(8))) short short8;
typedef __attribute__((ext_vector_type(4))) float f32x4;

__device__ __forceinline__ unsigned short f2bf(float f) {
    unsigned u = __float_as_uint(f);
    u += 0x7FFFu + ((u >> 16) & 1u);
    return (unsigned short)(u >> 16);
}

__device__ __forceinline__ short8 pack8(const float4& lo, const float4& hi) {
    short8 s;
    s[0] = (short)f2bf(lo.x); s[1] = (short)f2bf(lo.y);
    s[2] = (short)f2bf(lo.z); s[3] = (short)f2bf(lo.w);
    s[4] = (short)f2bf(hi.x); s[5] = (short)f2bf(hi.y);
    s[6] = (short)f2bf(hi.z); s[7] = (short)f2bf(hi.w);
    return s;
}

// async 16B global -> LDS (DMA, no VGPR round trip)
__device__ __forceinline__ void gld16u(unsigned short* l, const unsigned short* g) {
    __builtin_amdgcn_global_load_lds(
        (const __attribute__((address_space(1))) unsigned int*)g,
        (__attribute__((address_space(3))) unsigned int*)l, 16, 0, 0);
}

// ---------- init: zero xgPart (8 copies) + dPart ----------
__global__ __launch_bounds__(256) void k_init(float4* xgPart4, float4* dPart4) {
    int i = blockIdx.x * 256 + threadIdx.x;
    if (i < NCOPY * NB * EMB / 4) xgPart4[i] = (float4){0.f, 0.f, 0.f, 0.f};
    else dPart4[i - NCOPY * NB * EMB / 4] = (float4){0.f, 0.f, 0.f, 0.f};
}

// ---------- prep: W_feat -> bf16 chunked layout Wt2[k>>3][col][k&7] ----------
__global__ __launch_bounds__(256) void k_prep(const float* __restrict__ Wf,
                                              unsigned short* __restrict__ Wt2) {
    int b = blockIdx.x, t = threadIdx.x;            // b = k index, t = col
    float v = Wf[(size_t)b * EMB + t];              // W_feat[k=b][col=t]
    Wt2[((size_t)(b >> 3) << 11) + (t << 3) + (b & 7)] = f2bf(v);
}

// ---------- fused: gate + exp + bf16 MFMA feat GEMM + weighted segment reduce ----------
// 256 threads (4 waves, wr x wc = 2x2). Each block: stage FULL B (128 KB bf16) into
// LDS once, then process TPB_TILES consecutive 64-row tiles. A loads go direct
// global->reg (32 float4 burst per wave per tile), pack to bf16, gate for free.
// MFMA loop is barrier-free. 1 block/CU (LDS-bound).
__global__ __launch_bounds__(256, 1) void k_fused(const float* __restrict__ x,
                                                  const unsigned short* __restrict__ Wt2,
                                                  const float* __restrict__ wm,
                                                  const float* __restrict__ bfeat,
                                                  const int* __restrict__ bind,
                                                  float* __restrict__ dPart,
                                                  float* __restrict__ xgPart) {
    __shared__ unsigned short bbuf[32 * 2048];   // 128 KB: full B, [k>>3][col][k&7]
    __shared__ float wm_s[256];
    __shared__ float w_s[64];
    __shared__ float pxg[2][256];
    __shared__ float pden[2];
    __shared__ int   seg_s[64];
    __shared__ int   segid_s[4];
    __shared__ int   uni_s[4];

    const int t    = threadIdx.x;
    const int lane = t & 63;
    const int w    = t >> 6;
    const int wr   = w >> 1, wc = w & 1;
    const int fr   = lane & 15;
    const int fg   = lane >> 4;
    const int cp   = blockIdx.x & (NCOPY - 1);

    // ---- stage full B once: straight 128 KB contiguous DMA copy ----
#pragma unroll
    for (int q = 0; q < 32; q++)
        gld16u(&bbuf[q * 2048 + t * 8], Wt2 + ((size_t)q << 11) + t * 8);
    wm_s[t] = wm[t];
    __syncthreads();   // B staged (barrier drains vmcnt) + wm_s visible

    for (int tt = 0; tt < TPB_TILES; tt++) {
        const size_t r0 = ((size_t)blockIdx.x * TPB_TILES + tt) * 64;
        if (tt > 0) __syncthreads();   // previous tile's flush reads done; LDS reusable
        if (t < 64) seg_s[t] = bind[r0 + t];
        pxg[0][t] = 0.f;
        pxg[1][t] = 0.f;
        if (t < 2) pden[t] = 0.f;

        // ---- A: 32-deep float4 burst into registers ----
        const float* xb0 = x + (r0 + wr * 32 + fr) * EMB + fg * 8;
        const float* xb1 = xb0 + (size_t)16 * EMB;
        float4 lo0[8], hi0[8], lo1[8], hi1[8];
#pragma unroll
        for (int ks = 0; ks < 8; ks++) {
            lo0[ks] = *reinterpret_cast<const float4*>(xb0 + ks * 32);
            hi0[ks] = *reinterpret_cast<const float4*>(xb0 + ks * 32 + 4);
            lo1[ks] = *reinterpret_cast<const float4*>(xb1 + ks * 32);
            hi1[ks] = *reinterpret_cast<const float4*>(xb1 + ks * 32 + 4);
        }

        // ---- gate partials + pack to bf16 fragments ----
        float gp0 = 0.f, gp1 = 0.f;
        short8 ab0[8], ab1[8];
#pragma unroll
        for (int ks = 0; ks < 8; ks++) {
            const float4 wa  = *reinterpret_cast<const float4*>(&wm_s[ks * 32 + fg * 8]);
            const float4 wbv = *reinterpret_cast<const float4*>(&wm_s[ks * 32 + fg * 8 + 4]);
            gp0 += lo0[ks].x * wa.x + lo0[ks].y * wa.y + lo0[ks].z * wa.z + lo0[ks].w * wa.w
                 + hi0[ks].x * wbv.x + hi0[ks].y * wbv.y + hi0[ks].z * wbv.z + hi0[ks].w * wbv.w;
            gp1 += lo1[ks].x * wa.x + lo1[ks].y * wa.y + lo1[ks].z * wa.z + lo1[ks].w * wa.w
                 + hi1[ks].x * wbv.x + hi1[ks].y * wbv.y + hi1[ks].z * wbv.z + hi1[ks].w * wbv.w;
            ab0[ks] = pack8(lo0[ks], hi0[ks]);
            ab1[ks] = pack8(lo1[ks], hi1[ks]);
        }

        // ---- MFMA loop: pure reg + read-only LDS B, no barriers ----
        f32x4 acc[2][8];
#pragma unroll
        for (int m = 0; m < 2; m++)
#pragma unroll
            for (int n = 0; n < 8; n++) acc[m][n] = (f32x4){0.f, 0.f, 0.f, 0.f};

#pragma unroll
        for (int ks = 0; ks < 8; ks++) {
            short8 b[8];
#pragma unroll
            for (int n = 0; n < 8; n++)
                b[n] = *reinterpret_cast<const short8*>(
                    &bbuf[(ks * 4 + fg) * 2048 + ((wc * 128 + n * 16 + fr) << 3)]);
#pragma unroll
            for (int n = 0; n < 8; n++) {
                acc[0][n] = __builtin_amdgcn_mfma_f32_16x16x32_bf16(ab0[ks], b[n], acc[0][n], 0, 0, 0);
                acc[1][n] = __builtin_amdgcn_mfma_f32_16x16x32_bf16(ab1[ks], b[n], acc[1][n], 0, 0, 0);
            }
        }

        // ---- gate -> e ----
        gp0 += __shfl_xor(gp0, 16, 64); gp0 += __shfl_xor(gp0, 32, 64);
        gp1 += __shfl_xor(gp1, 16, 64); gp1 += __shfl_xor(gp1, 32, 64);
        // exp(b_mask) cancels in the softmax -> dropped
        if (wc == 0 && lane < 16) {
            w_s[wr * 32 + lane]      = expf(gp0);
            w_s[wr * 32 + 16 + lane] = expf(gp1);
        }
        __syncthreads();   // w_s + seg_s + pxg zeroing visible

        const int sid0 = seg_s[0];
        const int sid1 = seg_s[63];
        if (t < 4) {
            int s0 = seg_s[t * 16], ok = 1;
#pragma unroll
            for (int i = 1; i < 16; i++) ok &= (seg_s[t * 16 + i] == s0);
            segid_s[t] = s0;
            uni_s[t]   = ok;
        }
        __syncthreads();   // uni_s/segid_s visible

        // ---- denom partials (LDS slots, global fallback for >2-segment tiles) ----
        if (t < 4) {
            if (uni_s[t]) {
                float s = 0.f;
#pragma unroll
                for (int i = 0; i < 16; i++) s += w_s[t * 16 + i];
                const int sid = segid_s[t];
                if (sid == sid0)      atomicAdd(&pden[0], s);
                else if (sid == sid1) atomicAdd(&pden[1], s);
                else atomicAdd(&dPart[cp * NB + sid], s);
            } else {
                for (int i = 0; i < 16; i++) {
                    const int sd = seg_s[t * 16 + i];
                    const float e = w_s[t * 16 + i];
                    if (sd == sid0)      atomicAdd(&pden[0], e);
                    else if (sd == sid1) atomicAdd(&pden[1], e);
                    else atomicAdd(&dPart[cp * NB + sd], e);
                }
            }
        }

        // ---- epilogue: bias -> leaky -> *e -> segmented reduce -> LDS slots ----
#pragma unroll
        for (int m = 0; m < 2; m++) {
            const int g    = wr * 2 + m;
            const int uni  = uni_s[g];
            const int sid  = segid_s[g];
            const int rowb = wr * 32 + m * 16;
#pragma unroll
            for (int n = 0; n < 8; n++) {
                const int col = wc * 128 + n * 16 + fr;
                const float bia = bfeat[col];
                float vr[4];
#pragma unroll
                for (int r = 0; r < 4; r++) {
                    const int row = rowb + fg * 4 + r;
                    float v = acc[m][n][r] + bia;
                    v = (v >= 0.f) ? v : SLOPE * v;
                    vr[r] = v * w_s[row];
                }
                if (uni) {
                    float s = vr[0] + vr[1] + vr[2] + vr[3];
                    s += __shfl_xor(s, 16, 64);
                    s += __shfl_xor(s, 32, 64);
                    if (fg == 0) {
                        if (sid == sid0)      atomicAdd(&pxg[0][col], s);
                        else if (sid == sid1) atomicAdd(&pxg[1][col], s);
                        else atomicAdd(&xgPart[((size_t)(cp * NB + sid) << 8) + col], s);
                    }
                } else {
#pragma unroll
                    for (int r = 0; r < 4; r++) {
                        const int sd = seg_s[rowb + fg * 4 + r];
                        if (sd == sid0)      atomicAdd(&pxg[0][col], vr[r]);
                        else if (sd == sid1) atomicAdd(&pxg[1][col], vr[r]);
                        else atomicAdd(&xgPart[((size_t)(cp * NB + sd) << 8) + col], vr[r]);
                    }
                }
            }
        }
        __syncthreads();   // pxg complete

        // ---- flush tile partials into XCD-striped copies ----
        atomicAdd(&xgPart[((size_t)(cp * NB + sid0) << 8) + t], pxg[0][t]);
        if (sid1 != sid0)
            atomicAdd(&xgPart[((size_t)(cp * NB + sid1) << 8) + t], pxg[1][t]);
        if (t == 0) atomicAdd(&dPart[cp * NB + sid0], pden[0]);
        if (t == 1 && sid1 != sid0) atomicAdd(&dPart[cp * NB + sid1], pden[1]);
    }
}

// ---------- out = leaky_relu([xg/denom, xg_prev] @ W_t + b_t) + xg_prev ----------
__global__ __launch_bounds__(256) void k_out(const float* __restrict__ xgPart,
                                             const float* __restrict__ dPart,
                                             const float* __restrict__ xgp,
                                             const float* __restrict__ Wtr,
                                             const float* __restrict__ bt,
                                             float* __restrict__ out) {
    __shared__ float h[8][512];
    const int c  = threadIdx.x;
    const int b0 = blockIdx.x * 8;
#pragma unroll
    for (int r = 0; r < 8; r++) {
        const int b = b0 + r;
        float den = 0.f, s = 0.f;
#pragma unroll
        for (int cpy = 0; cpy < NCOPY; cpy++) {
            den += dPart[cpy * NB + b];
            s   += xgPart[((size_t)(cpy * NB + b) << 8) + c];
        }
        h[r][c]       = s / fmaxf(den, 1e-16f);
        h[r][EMB + c] = xgp[(size_t)b * EMB + c];
    }
    __syncthreads();
    float acc[8] = {0.f, 0.f, 0.f, 0.f, 0.f, 0.f, 0.f, 0.f};
    for (int k = 0; k < 2 * EMB; k++) {
        float wv = Wtr[(size_t)k * EMB + c];
#pragma unroll
        for (int r = 0; r < 8; r++) acc[r] += h[r][k] * wv;
    }
#pragma unroll
    for (int r = 0; r < 8; r++) {
        float v = acc[r] + bt[c];
        v = (v >= 0.f) ? v : SLOPE * v;
        out[(size_t)(b0 + r) * EMB + c] = v + xgp[(size_t)(b0 + r) * EMB + c];
    }
}

extern "C" void kernel_launch(void* const* d_in, const int* in_sizes, int n_in,
                              void* d_out, int out_size, void* d_ws, size_t ws_size,
                              hipStream_t stream) {
    const float* xgp  = (const float*)d_in[0];
    const float* x    = (const float*)d_in[1];
    const int*   bind = (const int*)d_in[2];
    const float* Wm   = (const float*)d_in[3];
    const float* Wf   = (const float*)d_in[5];
    const float* bf   = (const float*)d_in[6];
    const float* Wtr  = (const float*)d_in[7];
    const float* bt   = (const float*)d_in[8];
    float* out = (float*)d_out;

    char* ws = (char*)d_ws;
    unsigned short* Wt2    = (unsigned short*)ws;                 // 128 KB (chunked)
    float*          dPart  = (float*)(ws + 131072);               // 8*512 f32 = 16 KB
    float*          xgPart = (float*)(ws + 131072 + 16384);       // 8*512*256 f32 = 4 MB

    hipLaunchKernelGGL(k_init,  dim3(1028),                     dim3(256), 0, stream,
                       (float4*)xgPart, (float4*)dPart);
    hipLaunchKernelGGL(k_prep,  dim3(256),                      dim3(256), 0, stream, Wf, Wt2);
    hipLaunchKernelGGL(k_fused, dim3(NROWS / (64 * TPB_TILES)), dim3(256), 0, stream,
                       x, Wt2, Wm, bf, bind, dPart, xgPart);
    hipLaunchKernelGGL(k_out,   dim3(NB / 8),                   dim3(256), 0, stream,
                       xgPart, dPart, xgp, Wtr, bt, out);
}

// Round 11
// 142.640 us; speedup vs baseline: 1.6499x; 1.6499x over previous
//
#include <hip/hip_runtime.h>
#include <cstdint>
#include <cstddef>

#define NROWS 262144
#define EMB 256
#define NB 512
#define NCOPY 8
#define SLOPE 0.01f

typedef __attribute__((ext_vector_type(8))) short short8;
typedef __attribute__((ext_vector_type(4))) float f32x4;

__device__ __forceinline__ unsigned short f2bf(float f) {
    unsigned u = __float_as_uint(f);
    u += 0x7FFFu + ((u >> 16) & 1u);
    return (unsigned short)(u >> 16);
}

__device__ __forceinline__ short8 pack8(const float4& lo, const float4& hi) {
    short8 s;
    s[0] = (short)f2bf(lo.x); s[1] = (short)f2bf(lo.y);
    s[2] = (short)f2bf(lo.z); s[3] = (short)f2bf(lo.w);
    s[4] = (short)f2bf(hi.x); s[5] = (short)f2bf(hi.y);
    s[6] = (short)f2bf(hi.z); s[7] = (short)f2bf(hi.w);
    return s;
}

// async 16B global -> LDS (DMA, no VGPR round trip)
__device__ __forceinline__ void gld16f(float* l, const float* g) {
    __builtin_amdgcn_global_load_lds(
        (const __attribute__((address_space(1))) unsigned int*)g,
        (__attribute__((address_space(3))) unsigned int*)l, 16, 0, 0);
}
__device__ __forceinline__ void gld16u(unsigned short* l, const unsigned short* g) {
    __builtin_amdgcn_global_load_lds(
        (const __attribute__((address_space(1))) unsigned int*)g,
        (__attribute__((address_space(3))) unsigned int*)l, 16, 0, 0);
}

// ---------- init: zero xgPart (8 copies) + dPart ----------
__global__ __launch_bounds__(256) void k_init(float4* xgPart4, float4* dPart4) {
    int i = blockIdx.x * 256 + threadIdx.x;
    if (i < NCOPY * NB * EMB / 4) xgPart4[i] = (float4){0.f, 0.f, 0.f, 0.f};
    else dPart4[i - NCOPY * NB * EMB / 4] = (float4){0.f, 0.f, 0.f, 0.f};
}

// ---------- prep: W_feat -> bf16 chunked layout Wt2[k>>3][col][k&7] ----------
__global__ __launch_bounds__(256) void k_prep(const float* __restrict__ Wf,
                                              unsigned short* __restrict__ Wt2) {
    int b = blockIdx.x, t = threadIdx.x;            // b = k index, t = col
    float v = Wf[(size_t)b * EMB + t];              // W_feat[k=b][col=t]
    Wt2[((size_t)(b >> 3) << 11) + (t << 3) + (b & 7)] = f2bf(v);
}

// stage K-step (32 k) into buffer B: A 128x32 f32 (row-chunk XOR swizzled src),
// B = 4 contiguous 4KB slabs of Wt2. 4 DMA instructions per thread (512 threads).
#define STAGE(B, KT) do {                                                         \
    _Pragma("unroll")                                                             \
    for (int q = 0; q < 2; q++) {                                                 \
        const int i_ = q * 512 + t;                                               \
        const int row_ = i_ >> 3, c_ = i_ & 7;                                    \
        const int cs_ = c_ ^ (row_ & 7);                                          \
        gld16f(&xbuf[B][i_ * 4], x + ((r0 + row_) << 8) + (KT) + (cs_ << 2));     \
    }                                                                             \
    _Pragma("unroll")                                                             \
    for (int q = 0; q < 2; q++) {                                                 \
        const int i_ = q * 512 + t;                                               \
        const int slab_ = i_ >> 8, off_ = i_ & 255;                               \
        gld16u(&bbuf[B][slab_ * 2048 + off_ * 8],                                 \
               Wt2 + (((size_t)((KT) >> 3) + slab_) << 11) + off_ * 8);           \
    }                                                                             \
} while (0)

// ---------- fused: gate + exp + bf16 MFMA feat GEMM + weighted segment reduce ----------
// 512 threads = 8 waves (wr 0..3 x wc 0..1). Tile 128 rows x 256 cols, BK=32,
// 8 K-steps, double-buffered DMA staging with counted vmcnt(4) (never 0 mid-loop).
// LDS 68 KB -> 2 blocks/CU = 16 waves/CU (50% occupancy).
__global__ __launch_bounds__(512, 4) void k_fused(const float* __restrict__ x,
                                                  const unsigned short* __restrict__ Wt2,
                                                  const float* __restrict__ wm,
                                                  const float* __restrict__ bfeat,
                                                  const int* __restrict__ bind,
                                                  float* __restrict__ dPart,
                                                  float* __restrict__ xgPart) {
    __shared__ float          xbuf[2][128 * 32];   // A: 2 x 16 KB
    __shared__ unsigned short bbuf[2][32 * 256];   // B: 2 x 16 KB, [k-chunk][col][8]
    __shared__ float wm_s[256];
    __shared__ float w_s[128];
    __shared__ float pxg[2][256];
    __shared__ float pden[2];
    __shared__ int   seg_s[128];
    __shared__ int   segid_s[8];
    __shared__ int   uni_s[8];

    const int t    = threadIdx.x;
    const int lane = t & 63;
    const int w    = t >> 6;
    const int wr   = w >> 1, wc = w & 1;   // wr: 32-row group 0..3, wc: 128-col half
    const int fr   = lane & 15;
    const int fg   = lane >> 4;
    const size_t r0 = (size_t)blockIdx.x * 128;
    const int cp   = blockIdx.x & (NCOPY - 1);

    if (t < 256) { wm_s[t] = wm[t]; pxg[0][t] = 0.f; pxg[1][t] = 0.f; }
    if (t < 128) seg_s[t] = bind[r0 + t];
    if (t < 2)   pden[t] = 0.f;

    // prologue: stage step 0
    STAGE(0, 0);

    f32x4 acc[2][8];
#pragma unroll
    for (int m = 0; m < 2; m++)
#pragma unroll
        for (int n = 0; n < 8; n++) acc[m][n] = (f32x4){0.f, 0.f, 0.f, 0.f};
    float gp0 = 0.f, gp1 = 0.f;

#pragma unroll
    for (int s = 0; s < 8; s++) {
        const int buf = s & 1;
        if (s < 7) STAGE(buf ^ 1, (s + 1) * 32);   // issue next step's 4 loads
        // counted wait: retire step-s's 4 loads; step-(s+1)'s stay in flight
        if (s < 7) asm volatile("s_waitcnt vmcnt(4)" ::: "memory");
        else       asm volatile("s_waitcnt vmcnt(0)" ::: "memory");
        __builtin_amdgcn_sched_barrier(0);
        __builtin_amdgcn_s_barrier();      // all waves' step-s data landed (+smem init @s=0)
        __builtin_amdgcn_sched_barrier(0);

        // ---- compute step s: pure LDS ----
        const float* xb = &xbuf[buf][0];
        const unsigned short* bb = &bbuf[buf][0];

        const float4 wa  = *reinterpret_cast<const float4*>(&wm_s[s * 32 + fg * 8]);
        const float4 wbv = *reinterpret_cast<const float4*>(&wm_s[s * 32 + fg * 8 + 4]);
        short8 a0, a1;
        {
            const int r  = wr * 32 + fr;
            const int sl = (fg * 2) ^ (r & 7);
            const float4 lo = *reinterpret_cast<const float4*>(&xb[r * 32 + sl * 4]);
            const float4 hi = *reinterpret_cast<const float4*>(&xb[r * 32 + (sl ^ 1) * 4]);
            gp0 += lo.x * wa.x + lo.y * wa.y + lo.z * wa.z + lo.w * wa.w
                 + hi.x * wbv.x + hi.y * wbv.y + hi.z * wbv.z + hi.w * wbv.w;
            a0 = pack8(lo, hi);
        }
        {
            const int r  = wr * 32 + 16 + fr;
            const int sl = (fg * 2) ^ (r & 7);
            const float4 lo = *reinterpret_cast<const float4*>(&xb[r * 32 + sl * 4]);
            const float4 hi = *reinterpret_cast<const float4*>(&xb[r * 32 + (sl ^ 1) * 4]);
            gp1 += lo.x * wa.x + lo.y * wa.y + lo.z * wa.z + lo.w * wa.w
                 + hi.x * wbv.x + hi.y * wbv.y + hi.z * wbv.z + hi.w * wbv.w;
            a1 = pack8(lo, hi);
        }
#pragma unroll
        for (int n = 0; n < 8; n++) {
            const short8 b = *reinterpret_cast<const short8*>(
                &bb[fg * 2048 + ((wc * 128 + n * 16 + fr) << 3)]);
            acc[0][n] = __builtin_amdgcn_mfma_f32_16x16x32_bf16(a0, b, acc[0][n], 0, 0, 0);
            acc[1][n] = __builtin_amdgcn_mfma_f32_16x16x32_bf16(a1, b, acc[1][n], 0, 0, 0);
        }

        // release buf[s&1]: all waves done reading before next iteration overwrites it
        asm volatile("s_waitcnt lgkmcnt(0)" ::: "memory");
        __builtin_amdgcn_sched_barrier(0);
        __builtin_amdgcn_s_barrier();
        __builtin_amdgcn_sched_barrier(0);
    }

    // ---- gate -> e ----
    gp0 += __shfl_xor(gp0, 16, 64); gp0 += __shfl_xor(gp0, 32, 64);
    gp1 += __shfl_xor(gp1, 16, 64); gp1 += __shfl_xor(gp1, 32, 64);
    // exp(b_mask) cancels in the softmax -> dropped
    if (wc == 0 && lane < 16) {
        w_s[wr * 32 + lane]      = expf(gp0);
        w_s[wr * 32 + 16 + lane] = expf(gp1);
    }
    if (t < 8) {
        int s0 = seg_s[t * 16], ok = 1;
#pragma unroll
        for (int i = 1; i < 16; i++) ok &= (seg_s[t * 16 + i] == s0);
        segid_s[t] = s0;
        uni_s[t]   = ok;
    }
    __syncthreads();

    const int sid0 = seg_s[0];
    const int sid1 = seg_s[127];

    // ---- denom partials (LDS slots, global fallback for >2-segment tiles) ----
    if (t < 8) {
        if (uni_s[t]) {
            float s = 0.f;
#pragma unroll
            for (int i = 0; i < 16; i++) s += w_s[t * 16 + i];
            const int sid = segid_s[t];
            if (sid == sid0)      atomicAdd(&pden[0], s);
            else if (sid == sid1) atomicAdd(&pden[1], s);
            else atomicAdd(&dPart[cp * NB + sid], s);
        } else {
            for (int i = 0; i < 16; i++) {
                const int sd = seg_s[t * 16 + i];
                const float e = w_s[t * 16 + i];
                if (sd == sid0)      atomicAdd(&pden[0], e);
                else if (sd == sid1) atomicAdd(&pden[1], e);
                else atomicAdd(&dPart[cp * NB + sd], e);
            }
        }
    }

    // ---- epilogue: bias -> leaky -> *e -> segmented reduce -> LDS slots ----
#pragma unroll
    for (int m = 0; m < 2; m++) {
        const int g    = wr * 2 + m;
        const int uni  = uni_s[g];
        const int sid  = segid_s[g];
        const int rowb = wr * 32 + m * 16;
#pragma unroll
        for (int n = 0; n < 8; n++) {
            const int col = wc * 128 + n * 16 + fr;
            const float bia = bfeat[col];
            float vr[4];
#pragma unroll
            for (int r = 0; r < 4; r++) {
                const int row = rowb + fg * 4 + r;
                float v = acc[m][n][r] + bia;
                v = (v >= 0.f) ? v : SLOPE * v;
                vr[r] = v * w_s[row];
            }
            if (uni) {
                float s = vr[0] + vr[1] + vr[2] + vr[3];
                s += __shfl_xor(s, 16, 64);
                s += __shfl_xor(s, 32, 64);
                if (fg == 0) {
                    if (sid == sid0)      atomicAdd(&pxg[0][col], s);
                    else if (sid == sid1) atomicAdd(&pxg[1][col], s);
                    else atomicAdd(&xgPart[((size_t)(cp * NB + sid) << 8) + col], s);
                }
            } else {
#pragma unroll
                for (int r = 0; r < 4; r++) {
                    const int sd = seg_s[rowb + fg * 4 + r];
                    if (sd == sid0)      atomicAdd(&pxg[0][col], vr[r]);
                    else if (sd == sid1) atomicAdd(&pxg[1][col], vr[r]);
                    else atomicAdd(&xgPart[((size_t)(cp * NB + sd) << 8) + col], vr[r]);
                }
            }
        }
    }
    __syncthreads();

    // ---- flush block partials into XCD-striped copies ----
    if (t < 256) {
        atomicAdd(&xgPart[((size_t)(cp * NB + sid0) << 8) + t], pxg[0][t]);
    } else if (sid1 != sid0) {
        atomicAdd(&xgPart[((size_t)(cp * NB + sid1) << 8) + (t - 256)], pxg[1][t - 256]);
    }
    if (t == 0) atomicAdd(&dPart[cp * NB + sid0], pden[0]);
    if (t == 1 && sid1 != sid0) atomicAdd(&dPart[cp * NB + sid1], pden[1]);
}

// ---------- out = leaky_relu([xg/denom, xg_prev] @ W_t + b_t) + xg_prev ----------
__global__ __launch_bounds__(256) void k_out(const float* __restrict__ xgPart,
                                             const float* __restrict__ dPart,
                                             const float* __restrict__ xgp,
                                             const float* __restrict__ Wtr,
                                             const float* __restrict__ bt,
                                             float* __restrict__ out) {
    __shared__ float h[8][512];
    const int c  = threadIdx.x;
    const int b0 = blockIdx.x * 8;
#pragma unroll
    for (int r = 0; r < 8; r++) {
        const int b = b0 + r;
        float den = 0.f, s = 0.f;
#pragma unroll
        for (int cpy = 0; cpy < NCOPY; cpy++) {
            den += dPart[cpy * NB + b];
            s   += xgPart[((size_t)(cpy * NB + b) << 8) + c];
        }
        h[r][c]       = s / fmaxf(den, 1e-16f);
        h[r][EMB + c] = xgp[(size_t)b * EMB + c];
    }
    __syncthreads();
    float acc[8] = {0.f, 0.f, 0.f, 0.f, 0.f, 0.f, 0.f, 0.f};
    for (int k = 0; k < 2 * EMB; k++) {
        float wv = Wtr[(size_t)k * EMB + c];
#pragma unroll
        for (int r = 0; r < 8; r++) acc[r] += h[r][k] * wv;
    }
#pragma unroll
    for (int r = 0; r < 8; r++) {
        float v = acc[r] + bt[c];
        v = (v >= 0.f) ? v : SLOPE * v;
        out[(size_t)(b0 + r) * EMB + c] = v + xgp[(size_t)(b0 + r) * EMB + c];
    }
}

extern "C" void kernel_launch(void* const* d_in, const int* in_sizes, int n_in,
                              void* d_out, int out_size, void* d_ws, size_t ws_size,
                              hipStream_t stream) {
    const float* xgp  = (const float*)d_in[0];
    const float* x    = (const float*)d_in[1];
    const int*   bind = (const int*)d_in[2];
    const float* Wm   = (const float*)d_in[3];
    const float* Wf   = (const float*)d_in[5];
    const float* bf   = (const float*)d_in[6];
    const float* Wtr  = (const float*)d_in[7];
    const float* bt   = (const float*)d_in[8];
    float* out = (float*)d_out;

    char* ws = (char*)d_ws;
    unsigned short* Wt2    = (unsigned short*)ws;                 // 128 KB (chunked)
    float*          dPart  = (float*)(ws + 131072);               // 8*512 f32 = 16 KB
    float*          xgPart = (float*)(ws + 131072 + 16384);       // 8*512*256 f32 = 4 MB

    hipLaunchKernelGGL(k_init,  dim3(1028),        dim3(256), 0, stream,
                       (float4*)xgPart, (float4*)dPart);
    hipLaunchKernelGGL(k_prep,  dim3(256),         dim3(256), 0, stream, Wf, Wt2);
    hipLaunchKernelGGL(k_fused, dim3(NROWS / 128), dim3(512), 0, stream,
                       x, Wt2, Wm, bf, bind, dPart, xgPart);
    hipLaunchKernelGGL(k_out,   dim3(NB / 8),      dim3(256), 0, stream,
                       xgPart, dPart, xgp, Wtr, bt, out);
}